// Round 6
// baseline (257.735 us; speedup 1.0000x reference)
//
#include <hip/hip_runtime.h>

typedef _Float16 half8 __attribute__((ext_vector_type(8)));
typedef float f32x4 __attribute__((ext_vector_type(4)));

#define B_ 256
#define K_ 512
#define D_ 256
#define H_ 256
#define NROWS (B_*K_)          // 131072
#define LNEPS 1e-5f
#define ITERS 16               // row-tiles of 32 per block
#define INV1024 (1.0f/1024.0f)

// LDS A layout: per 32-row tile, arrays h and l; row stride 528 B (33x16,
// bank shift 4/row); chunk c (16B, k-range [8c,8c+8)) lives at byte offset
// pos(c)*16 where pos(c) = (c>>1) + 16*(c&1). Writes (one chunk per thread)
// and reads (n16-major) are conflict-free.
#define ROWS_ 528
#define ASZ (32*ROWS_)          // 16896 per array
#define BUFSZ (2*ASZ)           // h + l = 33792 per buffer
#define LDS_BYTES (2*BUFSZ + 8192)   // 75776: 2 bufs + red[2][16][32] float2

// 1024 threads = 16 waves, 16 cols/wave (round-2 structure: best measured).
// ONE barrier per iter: stage-first schedule.
//   iter i: ln_stage(tile i+1 -> buf[p^1])   [reads of buf[p^1] ended
//           before barrier(i-1)]
//           prefetch tile i+2 -> xr          [reuses xr regs]
//           wave0: finalize red[p^1] (tile i-1) -> ws   [overlaps MFMA]
//           MFMA(buf[p]); epilogue -> red[p]
//           __syncthreads()
// red is double-buffered so the finalize needs no extra barrier.
__global__ __launch_bounds__(1024, 4) void mfma_main(
    const float* __restrict__ slots, const float* __restrict__ gamma,
    const float* __restrict__ beta,  const float* __restrict__ w1,
    const float* __restrict__ b1,    const float* __restrict__ w2,
    float* __restrict__ ws)
{
    extern __shared__ __align__(16) char smem[];
    float2* red = (float2*)(smem + 2*BUFSZ);     // [2][16][32]

    const int t    = threadIdx.x;
    const int lane = t & 63;
    const int wv   = t >> 6;        // 0..15
    const int quad = lane >> 4;     // 0..3
    const int n16  = lane & 15;
    const int srow = t >> 5;        // 0..31 staging row
    const int seg8 = t & 31;        // 8 d's (one chunk) per staging thread

    const int colB  = wv*16 + n16;  // B-frag load column (0..255)
    const int tile0 = blockIdx.x * ITERS;

    // ---- persistent B fragments (gamma folded) + b1' = b1 + beta.W1 ----
    half8 Bh[8], Bl[8];
    float bsum = 0.f;
    #pragma unroll
    for (int ks = 0; ks < 8; ++ks) {
        const int k0 = ks*32 + quad*8;
        half8 h, l;
        #pragma unroll
        for (int j = 0; j < 8; ++j) {
            const float w  = w1[(size_t)(k0 + j)*H_ + colB];
            bsum += beta[k0 + j] * w;
            const float wg = gamma[k0 + j] * w;
            const _Float16 hh = (_Float16)wg;
            h[j] = hh;
            l[j] = (_Float16)((wg - (float)hh) * 1024.0f);
        }
        Bh[ks] = h; Bl[ks] = l;
    }
    bsum += __shfl_xor(bsum, 16, 64);
    bsum += __shfl_xor(bsum, 32, 64);
    const float b1col = b1[colB] + bsum;   // valid for col colB (lane n16)

    // redistribute epilogue constants to D layout: col = base + quad*4 + reg
    float b1p[4], w20[4], w21[4];
    #pragma unroll
    for (int reg = 0; reg < 4; ++reg) {
        const int cq = quad*4 + reg;                    // 0..15
        b1p[reg] = __shfl(b1col, cq, 64);               // from lane cq
        const int col = wv*16 + cq;
        w20[reg] = w2[2*col + 0];
        w21[reg] = w2[2*col + 1];
    }

    // LN (xhat only) + fp16 split + permuted LDS store of one 32-row tile.
    // Each thread owns 8 d's (chunk c = seg8); row split over 32 lanes.
    auto ln_stage = [&](const float* xr, char* buf) {
        float s = 0.f;
        #pragma unroll
        for (int j = 0; j < 8; ++j) s += xr[j];
        s += __shfl_xor(s, 1, 64); s += __shfl_xor(s, 2, 64);
        s += __shfl_xor(s, 4, 64); s += __shfl_xor(s, 8, 64);
        s += __shfl_xor(s, 16, 64);
        const float mean = s * (1.f/256.f);
        float q = 0.f;
        #pragma unroll
        for (int j = 0; j < 8; ++j) { const float d = xr[j]-mean; q += d*d; }
        q += __shfl_xor(q, 1, 64); q += __shfl_xor(q, 2, 64);
        q += __shfl_xor(q, 4, 64); q += __shfl_xor(q, 8, 64);
        q += __shfl_xor(q, 16, 64);
        const float rstd = rsqrtf(q * (1.f/256.f) + LNEPS);
        half8 hh, ll;
        #pragma unroll
        for (int jj = 0; jj < 8; ++jj) {
            const float x = (xr[jj] - mean) * rstd;
            const _Float16 xh = (_Float16)x;
            hh[jj] = xh;
            ll[jj] = (_Float16)((x - (float)xh) * 1024.0f);
        }
        const int off = srow*ROWS_ + ((seg8>>1) + 16*(seg8&1)) * 16;
        *(half8*)(buf + off)       = hh;
        *(half8*)(buf + ASZ + off) = ll;
    };

    float xr[8];
    // prologue: stage tile0 into buffer 0; preload xr = tile 1
    {
        const float* sp = slots + ((size_t)tile0*32 + srow)*D_ + seg8*8;
        #pragma unroll
        for (int i4 = 0; i4 < 2; ++i4) {
            const float4 v = ((const float4*)sp)[i4];
            xr[4*i4+0]=v.x; xr[4*i4+1]=v.y; xr[4*i4+2]=v.z; xr[4*i4+3]=v.w;
        }
        ln_stage(xr, smem);
        const float* sp1 = slots + ((size_t)(tile0+1)*32 + srow)*D_ + seg8*8;
        #pragma unroll
        for (int i4 = 0; i4 < 2; ++i4) {
            const float4 v = ((const float4*)sp1)[i4];
            xr[4*i4+0]=v.x; xr[4*i4+1]=v.y; xr[4*i4+2]=v.z; xr[4*i4+3]=v.w;
        }
    }
    __syncthreads();

    for (int i = 0; i < ITERS; ++i) {
        const int p = i & 1;

        // ---- stage tile i+1 into buf[p^1] (xr loaded last iter) ----
        if (i + 1 < ITERS)
            ln_stage(xr, smem + (size_t)(p^1)*BUFSZ);

        // ---- prefetch tile i+2 into xr (regs now free) ----
        if (i + 2 < ITERS) {
            const float* sp = slots + ((size_t)(tile0+i+2)*32 + srow)*D_ + seg8*8;
            #pragma unroll
            for (int i4 = 0; i4 < 2; ++i4) {
                const float4 v = ((const float4*)sp)[i4];
                xr[4*i4+0]=v.x; xr[4*i4+1]=v.y; xr[4*i4+2]=v.z; xr[4*i4+3]=v.w;
            }
        }

        // ---- wave0: finalize tile i-1 (red[p^1]) during others' MFMA ----
        if (i > 0 && t < 32) {
            const float2* rp = red + (p^1)*512;
            float p0 = 0.f, p1 = 0.f;
            #pragma unroll
            for (int w = 0; w < 16; ++w) {
                const float2 v = rp[w*32 + t];
                p0 += v.x; p1 += v.y;
            }
            const int grow = (tile0 + i - 1)*32 + t;
            ((float2*)ws)[grow] = make_float2(p0, p1);
        }

        // ---- MFMA: 3-pass split over K=256, operands swapped:
        //      D[m=col(quad*4+reg)][n=slotrow(n16)] ----
        const char* Ah = smem + (size_t)p*BUFSZ;
        const char* Al = Ah + ASZ;
        f32x4 Ch[2], Cl[2];
        Ch[0] = (f32x4)0.f; Ch[1] = (f32x4)0.f;
        Cl[0] = (f32x4)0.f; Cl[1] = (f32x4)0.f;

        #pragma unroll
        for (int ks = 0; ks < 8; ++ks) {
            const int c   = ks*4 + quad;                    // chunk index
            const int off = ((c>>1) + 16*(c&1)) * 16;       // pos(c)*16
            const half8 ah0 = *(const half8*)(Ah +  n16     *ROWS_ + off);
            const half8 ah1 = *(const half8*)(Ah + (n16+16) *ROWS_ + off);
            const half8 al0 = *(const half8*)(Al +  n16     *ROWS_ + off);
            const half8 al1 = *(const half8*)(Al + (n16+16) *ROWS_ + off);
            Ch[0] = __builtin_amdgcn_mfma_f32_16x16x32_f16(Bh[ks], ah0, Ch[0], 0,0,0);
            Ch[1] = __builtin_amdgcn_mfma_f32_16x16x32_f16(Bh[ks], ah1, Ch[1], 0,0,0);
            Cl[0] = __builtin_amdgcn_mfma_f32_16x16x32_f16(Bl[ks], ah0, Cl[0], 0,0,0);
            Cl[1] = __builtin_amdgcn_mfma_f32_16x16x32_f16(Bl[ks], ah1, Cl[1], 0,0,0);
            Cl[0] = __builtin_amdgcn_mfma_f32_16x16x32_f16(Bh[ks], al0, Cl[0], 0,0,0);
            Cl[1] = __builtin_amdgcn_mfma_f32_16x16x32_f16(Bh[ks], al1, Cl[1], 0,0,0);
        }

        // ---- epilogue: relu + w2; reduce 4 regs in-register + 2 shfl ----
        #pragma unroll
        for (int rs = 0; rs < 2; ++rs) {
            float p0 = 0.f, p1 = 0.f;
            #pragma unroll
            for (int reg = 0; reg < 4; ++reg) {
                float hv = Ch[rs][reg] + Cl[rs][reg]*INV1024 + b1p[reg];
                hv = fmaxf(hv, 0.f);
                p0 = fmaf(hv, w20[reg], p0);
                p1 = fmaf(hv, w21[reg], p1);
            }
            p0 += __shfl_xor(p0, 16, 64); p1 += __shfl_xor(p1, 16, 64);
            p0 += __shfl_xor(p0, 32, 64); p1 += __shfl_xor(p1, 32, 64);
            if (lane < 16)                       // quad 0 holds the total
                red[p*512 + wv*32 + rs*16 + n16] = make_float2(p0, p1);
        }

        __syncthreads();
    }

    // ---- finalize last tile (red written before final barrier) ----
    if (t < 32) {
        const float2* rp = red + ((ITERS-1)&1)*512;
        float p0 = 0.f, p1 = 0.f;
        #pragma unroll
        for (int w = 0; w < 16; ++w) {
            const float2 v = rp[w*32 + t];
            p0 += v.x; p1 += v.y;
        }
        const int grow = (tile0 + ITERS - 1)*32 + t;
        ((float2*)ws)[grow] = make_float2(p0, p1);
    }
}

// Combine: one block per batch row. Gumbel decision, soft prob, fused
// lower-bound fixup (single writer per out element).
__global__ __launch_bounds__(512) void combine(
    const float* __restrict__ ws, const float* __restrict__ b2,
    const float* __restrict__ u,  const float* __restrict__ rk,
    float* __restrict__ out)
{
    __shared__ unsigned long long best[8];
    __shared__ int cnts[8];
    __shared__ int s_need, s_kbest;
    const int b = blockIdx.x;
    const int k = threadIdx.x;          // 0..511
    const int row = b*K_ + k;
    const int wv = k >> 6;

    const float2 q0 = ((const float2*)ws)[row];
    const float l0 = b2[0] + q0.x;
    const float l1 = b2[1] + q0.y;
    const float2 uu = ((const float2*)u)[row];
    const float g0 = -logf(-logf(uu.x));
    const float g1 = -logf(-logf(uu.y));
    const bool keep = (l1 + g1) > (l0 + g0);
    out[NROWS + row] = 1.f / (1.f + expf(l0 - l1));

    unsigned long long comb = 0;
    if (!keep)
        comb = ((unsigned long long)__float_as_uint(rk[row]) << 32)
             | (unsigned)(K_ - 1 - k);
    const int wcount = __popcll(__ballot(keep));
    #pragma unroll
    for (int off = 32; off >= 1; off >>= 1) {
        const unsigned long long o = __shfl_xor(comb, off, 64);
        if (o > comb) comb = o;
    }
    if ((k & 63) == 0) { best[wv] = comb; cnts[wv] = wcount; }
    __syncthreads();
    if (k == 0) {
        int tot = 0; unsigned long long bc = 0;
        #pragma unroll
        for (int w = 0; w < 8; ++w) { tot += cnts[w]; if (best[w] > bc) bc = best[w]; }
        s_need  = (tot == 0);
        s_kbest = (K_ - 1) - (int)(bc & 0xffffffffu);
    }
    __syncthreads();
    const bool m = keep || (s_need && (k == s_kbest));
    out[row] = m ? 1.f : 0.f;
}

extern "C" void kernel_launch(void* const* d_in, const int* in_sizes, int n_in,
                              void* d_out, int out_size, void* d_ws, size_t ws_size,
                              hipStream_t stream) {
    const float* slots = (const float*)d_in[0];
    const float* gamma = (const float*)d_in[1];
    const float* beta  = (const float*)d_in[2];
    const float* w1    = (const float*)d_in[3];
    const float* b1    = (const float*)d_in[4];
    const float* w2    = (const float*)d_in[5];
    const float* b2    = (const float*)d_in[6];
    const float* u     = (const float*)d_in[7];
    const float* rk    = (const float*)d_in[8];
    float* out = (float*)d_out;
    float* ws  = (float*)d_ws;   // NROWS float2 = 1 MB

    hipLaunchKernelGGL(mfma_main, dim3(B_), dim3(1024), LDS_BYTES, stream,
                       slots, gamma, beta, w1, b1, w2, ws);
    hipLaunchKernelGGL(combine, dim3(B_), dim3(512), 0, stream,
                       ws, b2, u, rk, out);
}

// Round 7
// 257.226 us; speedup vs baseline: 1.0020x; 1.0020x over previous
//
#include <hip/hip_runtime.h>

typedef _Float16 half8 __attribute__((ext_vector_type(8)));
typedef float f32x4 __attribute__((ext_vector_type(4)));

#define B_ 256
#define K_ 512
#define D_ 256
#define H_ 256
#define NROWS (B_*K_)          // 131072
#define LNEPS 1e-5f
#define ITERS 16               // row-tiles of 32 per block
#define INV1024 (1.0f/1024.0f)

// LDS A layout: per 32-row tile, arrays h and l; row stride 528 B (33x16,
// bank shift 4/row); chunk c (16B, k-range [8c,8c+8)) lives at byte offset
// pos(c)*16 where pos(c) = (c>>1) + 16*(c&1). Writes (one chunk per thread)
// and reads (n16-major) are conflict-free.
#define ROWS_ 528
#define ASZ (32*ROWS_)          // 16896 per array
#define BUFSZ (2*ASZ)           // h + l = 33792 per buffer
// LDS map: [0,2*BUFSZ) A bufs | red[2][16][32] f2 8192 | logits[512] f2 4096
//          | aux 128 (best[8] ull, cnts[8], s_need, s_kbest)
#define RED_OFF   (2*BUFSZ)
#define LOG_OFF   (2*BUFSZ + 8192)
#define AUX_OFF   (2*BUFSZ + 8192 + 4096)
#define LDS_BYTES (AUX_OFF + 128)    // 80000 -> 1 block/CU

// 1024 threads = 16 waves, 16 cols/wave (round-2 structure: best measured,
// 64 VGPR + 64 AGPR, no spill). ONE barrier per iter, round-2 program order
// (MFMA -> epilogue -> finalize(prev tile) -> ln_stage), red double-buffered
// so the middle barrier is unnecessary. sched_barrier(0) pins the phase
// boundary so the allocator cannot merge live ranges (round-6 spill guard).
// Block b == batch row b: combine logic fused as a tail phase reading the
// per-row logits from LDS (no ws round-trip, no second dispatch).
__global__ __launch_bounds__(1024, 4) void mfma_main(
    const float* __restrict__ slots, const float* __restrict__ gamma,
    const float* __restrict__ beta,  const float* __restrict__ w1,
    const float* __restrict__ b1,    const float* __restrict__ w2,
    const float* __restrict__ b2,    const float* __restrict__ u,
    const float* __restrict__ rk,    float* __restrict__ out)
{
    extern __shared__ __align__(16) char smem[];
    float2* red    = (float2*)(smem + RED_OFF);   // [2][16][32]
    float2* logits = (float2*)(smem + LOG_OFF);   // [512]
    unsigned long long* best = (unsigned long long*)(smem + AUX_OFF);
    int* cnts = (int*)(smem + AUX_OFF + 64);      // [8]
    int* sNK  = (int*)(smem + AUX_OFF + 96);      // [0]=need [1]=kbest

    const int t    = threadIdx.x;
    const int lane = t & 63;
    const int wv   = t >> 6;        // 0..15
    const int quad = lane >> 4;     // 0..3
    const int n16  = lane & 15;
    const int srow = t >> 5;        // 0..31 staging row
    const int seg8 = t & 31;        // 8 d's (one chunk) per staging thread

    const int colB  = wv*16 + n16;  // B-frag load column (0..255)
    const int tile0 = blockIdx.x * ITERS;

    // ---- persistent B fragments (gamma folded) + b1' = b1 + beta.W1 ----
    half8 Bh[8], Bl[8];
    float bsum = 0.f;
    #pragma unroll
    for (int ks = 0; ks < 8; ++ks) {
        const int k0 = ks*32 + quad*8;
        half8 h, l;
        #pragma unroll
        for (int j = 0; j < 8; ++j) {
            const float w  = w1[(size_t)(k0 + j)*H_ + colB];
            bsum += beta[k0 + j] * w;
            const float wg = gamma[k0 + j] * w;
            const _Float16 hh = (_Float16)wg;
            h[j] = hh;
            l[j] = (_Float16)((wg - (float)hh) * 1024.0f);
        }
        Bh[ks] = h; Bl[ks] = l;
    }
    bsum += __shfl_xor(bsum, 16, 64);
    bsum += __shfl_xor(bsum, 32, 64);
    const float b1col = b1[colB] + bsum;   // valid for col colB (lane n16)

    // redistribute epilogue constants to D layout: col = base + quad*4 + reg
    float b1p[4], w20[4], w21[4];
    #pragma unroll
    for (int reg = 0; reg < 4; ++reg) {
        const int cq = quad*4 + reg;                    // 0..15
        b1p[reg] = __shfl(b1col, cq, 64);               // from lane cq
        const int col = wv*16 + cq;
        w20[reg] = w2[2*col + 0];
        w21[reg] = w2[2*col + 1];
    }

    // LN (xhat only) + fp16 split + permuted LDS store of one 32-row tile.
    // Each thread owns 8 d's (chunk c = seg8); row split over 32 lanes.
    auto ln_stage = [&](const float* xr, char* buf) {
        float s = 0.f;
        #pragma unroll
        for (int j = 0; j < 8; ++j) s += xr[j];
        s += __shfl_xor(s, 1, 64); s += __shfl_xor(s, 2, 64);
        s += __shfl_xor(s, 4, 64); s += __shfl_xor(s, 8, 64);
        s += __shfl_xor(s, 16, 64);
        const float mean = s * (1.f/256.f);
        float q = 0.f;
        #pragma unroll
        for (int j = 0; j < 8; ++j) { const float d = xr[j]-mean; q += d*d; }
        q += __shfl_xor(q, 1, 64); q += __shfl_xor(q, 2, 64);
        q += __shfl_xor(q, 4, 64); q += __shfl_xor(q, 8, 64);
        q += __shfl_xor(q, 16, 64);
        const float rstd = rsqrtf(q * (1.f/256.f) + LNEPS);
        half8 hh, ll;
        #pragma unroll
        for (int jj = 0; jj < 8; ++jj) {
            const float x = (xr[jj] - mean) * rstd;
            const _Float16 xh = (_Float16)x;
            hh[jj] = xh;
            ll[jj] = (_Float16)((x - (float)xh) * 1024.0f);
        }
        const int off = srow*ROWS_ + ((seg8>>1) + 16*(seg8&1)) * 16;
        *(half8*)(buf + off)       = hh;
        *(half8*)(buf + ASZ + off) = ll;
    };

    // prologue: stage tile0 into buffer 0
    {
        const float* sp = slots + ((size_t)tile0*32 + srow)*D_ + seg8*8;
        float xr0[8];
        #pragma unroll
        for (int i4 = 0; i4 < 2; ++i4) {
            const float4 v = ((const float4*)sp)[i4];
            xr0[4*i4+0]=v.x; xr0[4*i4+1]=v.y; xr0[4*i4+2]=v.z; xr0[4*i4+3]=v.w;
        }
        ln_stage(xr0, smem);
    }
    __syncthreads();

    for (int i = 0; i < ITERS; ++i) {
        const int p = i & 1;
        const bool have_next = (i + 1 < ITERS);

        // prefetch next tile (global latency hidden under MFMA phase)
        float xr[8];
        if (have_next) {
            const float* sp = slots + ((size_t)(tile0+i+1)*32 + srow)*D_ + seg8*8;
            #pragma unroll
            for (int i4 = 0; i4 < 2; ++i4) {
                const float4 v = ((const float4*)sp)[i4];
                xr[4*i4+0]=v.x; xr[4*i4+1]=v.y; xr[4*i4+2]=v.z; xr[4*i4+3]=v.w;
            }
        }

        // ---- MFMA: 3-pass split over K=256, operands swapped:
        //      D[m=col(quad*4+reg)][n=slotrow(n16)] ----
        const char* Ah = smem + (size_t)p*BUFSZ;
        const char* Al = Ah + ASZ;
        f32x4 Ch[2], Cl[2];
        Ch[0] = (f32x4)0.f; Ch[1] = (f32x4)0.f;
        Cl[0] = (f32x4)0.f; Cl[1] = (f32x4)0.f;

        #pragma unroll
        for (int ks = 0; ks < 8; ++ks) {
            const int c   = ks*4 + quad;                    // chunk index
            const int off = ((c>>1) + 16*(c&1)) * 16;       // pos(c)*16
            const half8 ah0 = *(const half8*)(Ah +  n16     *ROWS_ + off);
            const half8 ah1 = *(const half8*)(Ah + (n16+16) *ROWS_ + off);
            const half8 al0 = *(const half8*)(Al +  n16     *ROWS_ + off);
            const half8 al1 = *(const half8*)(Al + (n16+16) *ROWS_ + off);
            Ch[0] = __builtin_amdgcn_mfma_f32_16x16x32_f16(Bh[ks], ah0, Ch[0], 0,0,0);
            Ch[1] = __builtin_amdgcn_mfma_f32_16x16x32_f16(Bh[ks], ah1, Ch[1], 0,0,0);
            Cl[0] = __builtin_amdgcn_mfma_f32_16x16x32_f16(Bl[ks], ah0, Cl[0], 0,0,0);
            Cl[1] = __builtin_amdgcn_mfma_f32_16x16x32_f16(Bl[ks], ah1, Cl[1], 0,0,0);
            Cl[0] = __builtin_amdgcn_mfma_f32_16x16x32_f16(Bh[ks], al0, Cl[0], 0,0,0);
            Cl[1] = __builtin_amdgcn_mfma_f32_16x16x32_f16(Bh[ks], al1, Cl[1], 0,0,0);
        }

        // ---- epilogue: relu + w2; reduce 4 regs in-register + 2 shfl ----
        #pragma unroll
        for (int rs = 0; rs < 2; ++rs) {
            float p0 = 0.f, p1 = 0.f;
            #pragma unroll
            for (int reg = 0; reg < 4; ++reg) {
                float hv = Ch[rs][reg] + Cl[rs][reg]*INV1024 + b1p[reg];
                hv = fmaxf(hv, 0.f);
                p0 = fmaf(hv, w20[reg], p0);
                p1 = fmaf(hv, w21[reg], p1);
            }
            p0 += __shfl_xor(p0, 16, 64); p1 += __shfl_xor(p1, 16, 64);
            p0 += __shfl_xor(p0, 32, 64); p1 += __shfl_xor(p1, 32, 64);
            if (lane < 16)                       // quad 0 holds the total
                red[p*512 + wv*32 + rs*16 + n16] = make_float2(p0, p1);
        }

        // pin phase boundary: keep MFMA-phase and stage-phase live ranges
        // disjoint (anti-spill; round-6 lesson)
        __builtin_amdgcn_sched_barrier(0);

        // ---- wave0: finalize PREVIOUS tile (red[p^1], barrier-separated) ----
        if (i > 0 && t < 32) {
            const float2* rp = red + (p^1)*512;
            float p0 = 0.f, p1 = 0.f;
            #pragma unroll
            for (int w = 0; w < 16; ++w) {
                const float2 v = rp[w*32 + t];
                p0 += v.x; p1 += v.y;
            }
            logits[(i-1)*32 + t] = make_float2(p0, p1);
        }

        // ---- stage next tile into other buffer (reads of buf[p^1] all
        //      completed before barrier(i-1)) ----
        if (have_next)
            ln_stage(xr, smem + (size_t)(p^1)*BUFSZ);
        __syncthreads();
    }

    // ---- finalize last tile ----
    if (t < 32) {
        const float2* rp = red + ((ITERS-1)&1)*512;
        float p0 = 0.f, p1 = 0.f;
        #pragma unroll
        for (int w = 0; w < 16; ++w) {
            const float2 v = rp[w*32 + t];
            p0 += v.x; p1 += v.y;
        }
        logits[(ITERS-1)*32 + t] = make_float2(p0, p1);
    }
    __syncthreads();

    // ==== fused combine: gumbel decision, soft prob, lower-bound fixup ====
    // Waves 0..7 (t<512) own the block's 512 slots; logic verbatim from the
    // standalone combine kernel, logits read from LDS instead of ws.
    bool keep = false;
    if (t < 512) {
        const int k = t;
        const int row = blockIdx.x*K_ + k;
        const float2 lg = logits[k];
        const float l0 = b2[0] + lg.x;
        const float l1 = b2[1] + lg.y;
        const float2 uu = ((const float2*)u)[row];
        const float g0 = -logf(-logf(uu.x));
        const float g1 = -logf(-logf(uu.y));
        keep = (l1 + g1) > (l0 + g0);
        out[NROWS + row] = 1.f / (1.f + expf(l0 - l1));

        unsigned long long comb = 0;
        if (!keep)
            comb = ((unsigned long long)__float_as_uint(rk[row]) << 32)
                 | (unsigned)(K_ - 1 - k);
        const int wcount = __popcll(__ballot(keep));
        #pragma unroll
        for (int off = 32; off >= 1; off >>= 1) {
            const unsigned long long o = __shfl_xor(comb, off, 64);
            if (o > comb) comb = o;
        }
        if ((k & 63) == 0) { best[k >> 6] = comb; cnts[k >> 6] = wcount; }
    }
    __syncthreads();
    if (t == 0) {
        int tot = 0; unsigned long long bc = 0;
        #pragma unroll
        for (int w = 0; w < 8; ++w) { tot += cnts[w]; if (best[w] > bc) bc = best[w]; }
        sNK[0] = (tot == 0);
        sNK[1] = (K_ - 1) - (int)(bc & 0xffffffffu);
    }
    __syncthreads();
    if (t < 512) {
        const int row = blockIdx.x*K_ + t;
        const bool m = keep || (sNK[0] && (t == sNK[1]));
        out[row] = m ? 1.f : 0.f;
    }
}

extern "C" void kernel_launch(void* const* d_in, const int* in_sizes, int n_in,
                              void* d_out, int out_size, void* d_ws, size_t ws_size,
                              hipStream_t stream) {
    const float* slots = (const float*)d_in[0];
    const float* gamma = (const float*)d_in[1];
    const float* beta  = (const float*)d_in[2];
    const float* w1    = (const float*)d_in[3];
    const float* b1    = (const float*)d_in[4];
    const float* w2    = (const float*)d_in[5];
    const float* b2    = (const float*)d_in[6];
    const float* u     = (const float*)d_in[7];
    const float* rk    = (const float*)d_in[8];
    float* out = (float*)d_out;

    hipLaunchKernelGGL(mfma_main, dim3(B_), dim3(1024), LDS_BYTES, stream,
                       slots, gamma, beta, w1, b1, w2, b2, u, rk, out);
}

// Round 8
// 222.428 us; speedup vs baseline: 1.1587x; 1.1564x over previous
//
#include <hip/hip_runtime.h>

typedef _Float16 half8 __attribute__((ext_vector_type(8)));
typedef float f32x4 __attribute__((ext_vector_type(4)));

#define B_ 256
#define K_ 512
#define D_ 256
#define H_ 256
#define NROWS (B_*K_)          // 131072
#define LNEPS 1e-5f
#define ITERS 16               // row-tiles of 32 per block
#define INV1024 (1.0f/1024.0f)

// LDS A layout: per 32-row tile, arrays h and l; row stride 528 B (33x16,
// bank shift 4/row); chunk c (16B, k-range [8c,8c+8)) lives at byte offset
// pos(c)*16 where pos(c) = (c>>1) + 16*(c&1). Writes (one chunk per thread)
// and reads (n16-major) are conflict-free.
#define ROWS_ 528
#define ASZ (32*ROWS_)          // 16896 per array
#define BUFSZ (2*ASZ)           // h + l = 33792 per buffer
// LDS map: A bufs | red[16][32] f2 4096 | logits[512] f2 4096 | aux 128
#define RED_OFF   (2*BUFSZ)
#define LOG_OFF   (2*BUFSZ + 4096)
#define AUX_OFF   (2*BUFSZ + 8192)
#define LDS_BYTES (AUX_OFF + 128)    // 76032 -> 1 block/CU

// Round-2 loop VERBATIM (80.3 us, no spill): 1024 threads = 16 waves,
// 16 cols/wave, TWO barriers per iter. Evidence (r4/r6/r7): at the 128-reg
// cap, only the hardware barrier keeps staging and MFMA live ranges
// disjoint -- every 1-barrier variant spilled ~40 regs (WRITE_SIZE 32-42MB,
// +30us). Do not remove the barriers. Only change vs round 2: finalize
// writes logits to LDS (not ws), and the combine kernel is fused as a tail
// phase (block b == batch row b), killing the second dispatch + ws traffic.
__global__ __launch_bounds__(1024, 4) void mfma_main(
    const float* __restrict__ slots, const float* __restrict__ gamma,
    const float* __restrict__ beta,  const float* __restrict__ w1,
    const float* __restrict__ b1,    const float* __restrict__ w2,
    const float* __restrict__ b2,    const float* __restrict__ u,
    const float* __restrict__ rk,    float* __restrict__ out)
{
    extern __shared__ __align__(16) char smem[];
    float2* red    = (float2*)(smem + RED_OFF);   // [16][32]
    float2* logits = (float2*)(smem + LOG_OFF);   // [512]
    unsigned long long* best = (unsigned long long*)(smem + AUX_OFF);
    int* cnts = (int*)(smem + AUX_OFF + 64);      // [8]
    int* sNK  = (int*)(smem + AUX_OFF + 96);      // [0]=need [1]=kbest

    const int t    = threadIdx.x;
    const int lane = t & 63;
    const int wv   = t >> 6;        // 0..15
    const int quad = lane >> 4;     // 0..3
    const int n16  = lane & 15;
    const int srow = t >> 5;        // 0..31 staging row
    const int seg8 = t & 31;        // 8 d's (one chunk) per staging thread

    const int colB  = wv*16 + n16;  // B-frag load column (0..255)
    const int tile0 = blockIdx.x * ITERS;

    // ---- persistent B fragments (gamma folded) + b1' = b1 + beta.W1 ----
    half8 Bh[8], Bl[8];
    float bsum = 0.f;
    #pragma unroll
    for (int ks = 0; ks < 8; ++ks) {
        const int k0 = ks*32 + quad*8;
        half8 h, l;
        #pragma unroll
        for (int j = 0; j < 8; ++j) {
            const float w  = w1[(size_t)(k0 + j)*H_ + colB];
            bsum += beta[k0 + j] * w;
            const float wg = gamma[k0 + j] * w;
            const _Float16 hh = (_Float16)wg;
            h[j] = hh;
            l[j] = (_Float16)((wg - (float)hh) * 1024.0f);
        }
        Bh[ks] = h; Bl[ks] = l;
    }
    bsum += __shfl_xor(bsum, 16, 64);
    bsum += __shfl_xor(bsum, 32, 64);
    const float b1col = b1[colB] + bsum;   // valid for col colB (lane n16)

    // redistribute epilogue constants to D layout: col = base + quad*4 + reg
    float b1p[4], w20[4], w21[4];
    #pragma unroll
    for (int reg = 0; reg < 4; ++reg) {
        const int cq = quad*4 + reg;                    // 0..15
        b1p[reg] = __shfl(b1col, cq, 64);               // from lane cq
        const int col = wv*16 + cq;
        w20[reg] = w2[2*col + 0];
        w21[reg] = w2[2*col + 1];
    }

    // LN (xhat only) + fp16 split + permuted LDS store of one 32-row tile.
    // Each thread owns 8 d's (chunk c = seg8); row split over 32 lanes.
    auto ln_stage = [&](const float* xr, char* buf) {
        float s = 0.f;
        #pragma unroll
        for (int j = 0; j < 8; ++j) s += xr[j];
        s += __shfl_xor(s, 1, 64); s += __shfl_xor(s, 2, 64);
        s += __shfl_xor(s, 4, 64); s += __shfl_xor(s, 8, 64);
        s += __shfl_xor(s, 16, 64);
        const float mean = s * (1.f/256.f);
        float q = 0.f;
        #pragma unroll
        for (int j = 0; j < 8; ++j) { const float d = xr[j]-mean; q += d*d; }
        q += __shfl_xor(q, 1, 64); q += __shfl_xor(q, 2, 64);
        q += __shfl_xor(q, 4, 64); q += __shfl_xor(q, 8, 64);
        q += __shfl_xor(q, 16, 64);
        const float rstd = rsqrtf(q * (1.f/256.f) + LNEPS);
        half8 hh, ll;
        #pragma unroll
        for (int jj = 0; jj < 8; ++jj) {
            const float x = (xr[jj] - mean) * rstd;
            const _Float16 xh = (_Float16)x;
            hh[jj] = xh;
            ll[jj] = (_Float16)((x - (float)xh) * 1024.0f);
        }
        const int off = srow*ROWS_ + ((seg8>>1) + 16*(seg8&1)) * 16;
        *(half8*)(buf + off)       = hh;
        *(half8*)(buf + ASZ + off) = ll;
    };

    // prologue: stage tile0 into buffer 0
    {
        const float* sp = slots + ((size_t)tile0*32 + srow)*D_ + seg8*8;
        float xr0[8];
        #pragma unroll
        for (int i4 = 0; i4 < 2; ++i4) {
            const float4 v = ((const float4*)sp)[i4];
            xr0[4*i4+0]=v.x; xr0[4*i4+1]=v.y; xr0[4*i4+2]=v.z; xr0[4*i4+3]=v.w;
        }
        ln_stage(xr0, smem);
    }
    __syncthreads();

    for (int i = 0; i < ITERS; ++i) {
        const int p = i & 1;
        const bool have_next = (i + 1 < ITERS);

        // prefetch next tile (global latency hidden under MFMA phase)
        float xr[8];
        if (have_next) {
            const float* sp = slots + ((size_t)(tile0+i+1)*32 + srow)*D_ + seg8*8;
            #pragma unroll
            for (int i4 = 0; i4 < 2; ++i4) {
                const float4 v = ((const float4*)sp)[i4];
                xr[4*i4+0]=v.x; xr[4*i4+1]=v.y; xr[4*i4+2]=v.z; xr[4*i4+3]=v.w;
            }
        }

        // ---- MFMA: 3-pass split over K=256, operands swapped:
        //      D[m=col(quad*4+reg)][n=slotrow(n16)] ----
        const char* Ah = smem + (size_t)p*BUFSZ;
        const char* Al = Ah + ASZ;
        f32x4 Ch[2], Cl[2];
        Ch[0] = (f32x4)0.f; Ch[1] = (f32x4)0.f;
        Cl[0] = (f32x4)0.f; Cl[1] = (f32x4)0.f;

        #pragma unroll
        for (int ks = 0; ks < 8; ++ks) {
            const int c   = ks*4 + quad;                    // chunk index
            const int off = ((c>>1) + 16*(c&1)) * 16;       // pos(c)*16
            const half8 ah0 = *(const half8*)(Ah +  n16     *ROWS_ + off);
            const half8 ah1 = *(const half8*)(Ah + (n16+16) *ROWS_ + off);
            const half8 al0 = *(const half8*)(Al +  n16     *ROWS_ + off);
            const half8 al1 = *(const half8*)(Al + (n16+16) *ROWS_ + off);
            Ch[0] = __builtin_amdgcn_mfma_f32_16x16x32_f16(Bh[ks], ah0, Ch[0], 0,0,0);
            Ch[1] = __builtin_amdgcn_mfma_f32_16x16x32_f16(Bh[ks], ah1, Ch[1], 0,0,0);
            Cl[0] = __builtin_amdgcn_mfma_f32_16x16x32_f16(Bl[ks], ah0, Cl[0], 0,0,0);
            Cl[1] = __builtin_amdgcn_mfma_f32_16x16x32_f16(Bl[ks], ah1, Cl[1], 0,0,0);
            Cl[0] = __builtin_amdgcn_mfma_f32_16x16x32_f16(Bh[ks], al0, Cl[0], 0,0,0);
            Cl[1] = __builtin_amdgcn_mfma_f32_16x16x32_f16(Bh[ks], al1, Cl[1], 0,0,0);
        }

        // ---- epilogue: relu + w2; reduce 4 regs in-register + 2 shfl ----
        #pragma unroll
        for (int rs = 0; rs < 2; ++rs) {
            float p0 = 0.f, p1 = 0.f;
            #pragma unroll
            for (int reg = 0; reg < 4; ++reg) {
                float hv = Ch[rs][reg] + Cl[rs][reg]*INV1024 + b1p[reg];
                hv = fmaxf(hv, 0.f);
                p0 = fmaf(hv, w20[reg], p0);
                p1 = fmaf(hv, w21[reg], p1);
            }
            p0 += __shfl_xor(p0, 16, 64); p1 += __shfl_xor(p1, 16, 64);
            p0 += __shfl_xor(p0, 32, 64); p1 += __shfl_xor(p1, 32, 64);
            if (lane < 16)                       // quad 0 holds the total
                red[wv*32 + rs*16 + n16] = make_float2(p0, p1);
        }
        __syncthreads();

        // ---- finalize: combine 16 waves -> float2 logits in LDS ----
        if (t < 32) {
            float p0 = 0.f, p1 = 0.f;
            #pragma unroll
            for (int w = 0; w < 16; ++w) {
                const float2 v = red[w*32 + t];
                p0 += v.x; p1 += v.y;
            }
            logits[i*32 + t] = make_float2(p0, p1);
        }
        // ---- stage next tile into other buffer ----
        if (have_next)
            ln_stage(xr, smem + (size_t)(p^1)*BUFSZ);
        __syncthreads();
    }

    // ==== fused combine: gumbel decision, soft prob, lower-bound fixup ====
    // Waves 0..7 (t<512) own the block's 512 slots; logic verbatim from the
    // standalone combine kernel, logits read from LDS instead of ws.
    bool keep = false;
    if (t < 512) {
        const int k = t;
        const int row = blockIdx.x*K_ + k;
        const float2 lg = logits[k];
        const float l0 = b2[0] + lg.x;
        const float l1 = b2[1] + lg.y;
        const float2 uu = ((const float2*)u)[row];
        const float g0 = -logf(-logf(uu.x));
        const float g1 = -logf(-logf(uu.y));
        keep = (l1 + g1) > (l0 + g0);
        out[NROWS + row] = 1.f / (1.f + expf(l0 - l1));

        unsigned long long comb = 0;
        if (!keep)
            comb = ((unsigned long long)__float_as_uint(rk[row]) << 32)
                 | (unsigned)(K_ - 1 - k);
        const int wcount = __popcll(__ballot(keep));
        #pragma unroll
        for (int off = 32; off >= 1; off >>= 1) {
            const unsigned long long o = __shfl_xor(comb, off, 64);
            if (o > comb) comb = o;
        }
        if ((k & 63) == 0) { best[k >> 6] = comb; cnts[k >> 6] = wcount; }
    }
    __syncthreads();
    if (t == 0) {
        int tot = 0; unsigned long long bc = 0;
        #pragma unroll
        for (int w = 0; w < 8; ++w) { tot += cnts[w]; if (best[w] > bc) bc = best[w]; }
        sNK[0] = (tot == 0);
        sNK[1] = (K_ - 1) - (int)(bc & 0xffffffffu);
    }
    __syncthreads();
    if (t < 512) {
        const int row = blockIdx.x*K_ + t;
        const bool m = keep || (sNK[0] && (t == sNK[1]));
        out[row] = m ? 1.f : 0.f;
    }
}

extern "C" void kernel_launch(void* const* d_in, const int* in_sizes, int n_in,
                              void* d_out, int out_size, void* d_ws, size_t ws_size,
                              hipStream_t stream) {
    const float* slots = (const float*)d_in[0];
    const float* gamma = (const float*)d_in[1];
    const float* beta  = (const float*)d_in[2];
    const float* w1    = (const float*)d_in[3];
    const float* b1    = (const float*)d_in[4];
    const float* w2    = (const float*)d_in[5];
    const float* b2    = (const float*)d_in[6];
    const float* u     = (const float*)d_in[7];
    const float* rk    = (const float*)d_in[8];
    float* out = (float*)d_out;

    hipLaunchKernelGGL(mfma_main, dim3(B_), dim3(1024), LDS_BYTES, stream,
                       slots, gamma, beta, w1, b1, w2, b2, u, rk, out);
}